// Round 17
// baseline (80.513 us; speedup 1.0000x reference)
//
#include <hip/hip_runtime.h>
#include <hip/hip_bf16.h>
#include <math.h>

#define HH 128
#define WW 128
#define HW 16384
#define BATCH 8

// 2D tile geometry (fused kernel)
#define TR 8            // tile rows per block
#define TC 16           // tile cols per block
#define HALO 2
#define PR 12           // TR + 2*HALO
#define PC 20           // TC + 2*HALO
#define NPX (PR * PC)   // 240 patch pixels
#define PST 34          // dwords/px: 2 mod 32 -> 2-way banks on b128 (free)

typedef __attribute__((ext_vector_type(8))) _Float16 f16x8;
typedef __attribute__((ext_vector_type(2))) _Float16 f16x2;
typedef __attribute__((ext_vector_type(16))) float f32x16;
typedef __attribute__((ext_vector_type(4))) unsigned int u32x4;

union FragU { f16x8 v; unsigned int u[4]; u32x4 q; f16x2 h[4]; };

static __device__ __forceinline__ unsigned short f2h(float f) {
    _Float16 h = (_Float16)f;
    return *(unsigned short*)&h;
}
static __device__ __forceinline__ float h2f(unsigned short u) {
    _Float16 h = *(_Float16*)&u;
    return (float)h;
}

// f16 packed bilerp: 4 v_pk_fma_f16 per channel-pair; output IS the B-frag.
static __device__ __forceinline__ f16x8 bilerp_frag(
    u32x4 r00, u32x4 r01, u32x4 r10, u32x4 r11,
    f16x2 W0, f16x2 W1, f16x2 W2, f16x2 W3)
{
    FragU a, b, c, d, bf;
    a.q = r00; b.q = r01; c.q = r10; d.q = r11;
#pragma unroll
    for (int i = 0; i < 4; ++i) {
        f16x2 s = a.h[i] * W0;
        s = __builtin_elementwise_fma(b.h[i], W1, s);
        s = __builtin_elementwise_fma(c.h[i], W2, s);
        s = __builtin_elementwise_fma(d.h[i], W3, s);
        bf.h[i] = s;
    }
    return bf.v;
}

// plain stride-34 patch addressing
#define PADDR(PX, C) ((PX) * PST + ((C) << 2))

// per-kk phase-2 context (all fields accessed statically -> registers)
struct Ctx {
    f16x2 W0, W1, W2, W3;
    int p00, p01, p10, p11;   // patch pixel indices (valid iff inp)
    int g00, g01, g10, g11;   // global dword offsets (fallback)
    int inp;                  // wave-uniform in-patch flag
};

// ---------------------------------------------------------------------------
// Merged transform+prep kernel.
//   blocks [0,2048): x NCHW fp32 -> xT NHWC f16 (u32 pairs), LDS-tiled.
//   blocks [2048,2075): pack weights into 32x32x16 MFMA A-fragments (f16).
//     A lane l: row = l&31, k-elems j=0..7 -> channel c = s*16+8*(l>>5)+j
// ---------------------------------------------------------------------------
__global__ __launch_bounds__(256) void transform_prep_kernel(
    const float* __restrict__ x,
    unsigned int* __restrict__ xT,
    const float* __restrict__ weight,
    const float* __restrict__ offset_w,
    unsigned short* __restrict__ wA,
    unsigned short* __restrict__ owA)
{
    __shared__ unsigned int lds[64][33];
    int bid = blockIdx.x;
    int t = threadIdx.x;

    if (bid < 2048) {
        int b = bid & 7;                    // image -> XCD
        int pix0 = (bid >> 3) << 6;
        int px = t & 63;
        int cp0 = (t >> 6) * 8;

        const float* xb = x + (size_t)b * 64 * HW + pix0 + px;
#pragma unroll
        for (int it = 0; it < 8; ++it) {
            int cpair = cp0 + it;
            float lo = xb[(size_t)(2 * cpair) * HW];
            float hi = xb[(size_t)(2 * cpair + 1) * HW];
            lds[px][cpair] = ((unsigned int)f2h(hi) << 16) | f2h(lo);
        }
        __syncthreads();

        int wpx = t >> 2, qq = t & 3;
        unsigned int* dst = xT + ((size_t)b * HW + pix0 + wpx) * 32 + qq * 8;
        u32x4 a, c;
#pragma unroll
        for (int j = 0; j < 4; ++j) a[j] = lds[wpx][qq * 8 + j];
#pragma unroll
        for (int j = 0; j < 4; ++j) c[j] = lds[wpx][qq * 8 + 4 + j];
        *(u32x4*)dst = a;
        *(u32x4*)(dst + 4) = c;
        return;
    }

    // ---- prep branch ----
    int id = (bid - 2048) * 256 + t;
    if (id < 4608) {                        // 2*9*4*64
        int m = id / 2304;
        int rem = id % 2304;
        int kk = rem >> 8;
        int s = (rem >> 6) & 3;
        int l = id & 63;
        int cout = m * 32 + (l & 31);
        int cbase = s * 16 + 8 * (l >> 5);
#pragma unroll
        for (int j = 0; j < 8; ++j) {
            wA[id * 8 + j] = f2h(weight[(cout * 64 + cbase + j) * 9 + kk]);
        }
        return;
    }
    int id2 = id - 4608;
    if (id2 < 2304) {                       // 9*4*64
        int kk = id2 >> 8;
        int s = (id2 >> 6) & 3;
        int l = id2 & 63;
        int cout = l & 31;
        int cbase = s * 16 + 8 * (l >> 5);
#pragma unroll
        for (int j = 0; j < 8; ++j) {
            float v = (cout < 27) ? offset_w[(cout * 64 + cbase + j) * 9 + kk] : 0.0f;
            owA[id2 * 8 + j] = f2h(v);
        }
    }
}

// ---------------------------------------------------------------------------
// Fused kernel, LDS-patch v7 (f16 + phase-2 software pipeline).
//   vs r16: phase-2 corner ds_reads issued ONE s-step AHEAD (16 transient
//   VGPRs) so the ~120cy LDS latency hides under bilerp+MFMA of the current
//   step; incremental ky/kx (no runtime /3). Structure otherwise identical
//   (stride-34 patch, zeroed OOB pixels, per-wave f16 red, JIT A-frags,
//   one barrier). Spill sentinel: FETCH_SIZE (~8.7MB clean).
// ---------------------------------------------------------------------------
__global__ __launch_bounds__(256, 4) void fused_kernel(
    const unsigned int* __restrict__ xT,    // NHWC f16
    const unsigned short* __restrict__ wA,  // (2,9,4,64,8) f16
    const unsigned short* __restrict__ owA, // (9,4,64,8) f16
    const float* __restrict__ bias,         // (64,)
    const float* __restrict__ offset_b,     // (27,)
    float* __restrict__ out)                // (B,64,HW) f32
{
    __shared__ unsigned int patch[NPX * PST];       // 32.64 KB
    __shared__ unsigned short red[4][27][32];       // 6.91 KB per-wave off/mask

    int t = threadIdx.x;
    int lane = t & 63;
    int wid = t >> 6;
    int bid = blockIdx.x;
    int b = bid & 7;                        // image -> XCD
    int tile = bid >> 3;                    // 0..127
    int ho0 = (tile >> 3) * TR;
    int wo0 = (tile & 7) * TC;
    int py0 = ho0 - HALO;
    int px0 = wo0 - HALO;

    int q = lane & 31;                      // pixel within wave
    int hi = lane >> 5;                     // channel-half
    int ho = ho0 + 2 * wid + (q >> 4);
    int wo = wo0 + (q & 15);
    int p = ho * WW + wo;

    const unsigned int* xb = xT + (size_t)b * HW * 32;
    const f16x8* wAv = (const f16x8*)wA;
    const f16x8* owAv = (const f16x8*)owA;

    // ---------------- stage patch (coalesced; OOB pixels -> zero) ---------
#pragma unroll
    for (int it = 0; it < 8; ++it) {
        int id = it * 256 + t;
        if (id < NPX * 8) {                 // 1920 16B-chunks
            int px = id >> 3;               // 8 lanes = 1 pixel
            int c = id & 7;
            int row = px / PC;
            int col = px - row * PC;
            int iy = py0 + row;
            int ix = px0 + col;
            bool okpx = ((unsigned)iy < 128u) && ((unsigned)ix < 128u);
            int yc = min(max(iy, 0), HH - 1);
            int xc = min(max(ix, 0), WW - 1);
            u32x4 v = *(const u32x4*)(xb + (size_t)(yc * WW + xc) * 32 + c * 4);
#pragma unroll
            for (int j = 0; j < 4; ++j) v[j] = okpx ? v[j] : 0u;
            *(u32x4*)&patch[PADDR(px, c)] = v;
        }
    }
    __syncthreads();                        // the ONLY barrier

    // ---------------- phase 1: offset conv (no boundary code) -------------
    {
        f32x16 acc1 = {};
#pragma unroll
        for (int kk = 0; kk < 9; ++kk) {
            int jy = ho + kk / 3 - 1 - py0;     // always within patch
            int jx = wo + kk % 3 - 1 - px0;
            int ptap = jy * PC + jx;
#pragma unroll
            for (int s = 0; s < 4; ++s) {
                FragU bf;
                bf.q = *(const u32x4*)&patch[PADDR(ptap, 2 * s + hi)];
                acc1 = __builtin_amdgcn_mfma_f32_32x32x16_f16(
                    owAv[(kk * 4 + s) * 64 + lane], bf.v, acc1, 0, 0, 0);
            }
        }
        // bias + sigmoid -> per-wave f16 LDS slice; acc1 dies here.
#pragma unroll
        for (int r = 0; r < 16; ++r) {
            int cout = (r & 3) + 8 * (r >> 2) + 4 * hi;
            if (cout < 27) {
                float a = acc1[r] + offset_b[cout];
                if (cout >= 18) a = 1.0f / (1.0f + __expf(-a));
                red[wid][cout][q] = f2h(a);
            }
        }
    }

    // ---------------- phase 2: deformable conv (pipelined) ----------------
    f32x16 acc[2];
#pragma unroll
    for (int m = 0; m < 2; ++m) {
#pragma unroll
        for (int r = 0; r < 16; ++r) {
            acc[m][r] = bias[m * 32 + (r & 3) + 8 * (r >> 2) + 4 * hi];
        }
    }

#define MKCTX(KK, KY, KX, C) {                                              \
        float dy = h2f(red[wid][2 * (KK)][q]);                              \
        float dx = h2f(red[wid][2 * (KK) + 1][q]);                          \
        float mm = h2f(red[wid][18 + (KK)][q]);                             \
        float py_ = dy + (float)((KY) + ho - 1);                            \
        float px_ = dx + (float)((KX) + wo - 1);                            \
        float y0f = floorf(py_), x0f = floorf(px_);                         \
        float wy = py_ - y0f, wx = px_ - x0f;                               \
        int y0 = (int)y0f, x0 = (int)x0f;                                   \
        int y1 = y0 + 1, x1 = x0 + 1;                                       \
        bool y0ok = (unsigned)y0 < 128u, y1ok = (unsigned)y1 < 128u;        \
        bool x0ok = (unsigned)x0 < 128u, x1ok = (unsigned)x1 < 128u;        \
        float w0 = (y0ok && x0ok) ? (1.0f - wy) * (1.0f - wx) * mm : 0.0f;  \
        float w1 = (y0ok && x1ok) ? (1.0f - wy) * wx * mm : 0.0f;           \
        float w2 = (y1ok && x0ok) ? wy * (1.0f - wx) * mm : 0.0f;           \
        float w3 = (y1ok && x1ok) ? wy * wx * mm : 0.0f;                    \
        C.W0 = (f16x2){(_Float16)w0, (_Float16)w0};                         \
        C.W1 = (f16x2){(_Float16)w1, (_Float16)w1};                         \
        C.W2 = (f16x2){(_Float16)w2, (_Float16)w2};                         \
        C.W3 = (f16x2){(_Float16)w3, (_Float16)w3};                         \
        int y0c = min(max(y0, 0), 127), y1c = min(max(y1, 0), 127);         \
        int x0c = min(max(x0, 0), 127), x1c = min(max(x1, 0), 127);         \
        int jy0 = y0c - py0, jy1 = y1c - py0;                               \
        int jx0 = x0c - px0, jx1 = x1c - px0;                               \
        bool inp_ = ((unsigned)jy0 < (unsigned)PR) &&                       \
                    ((unsigned)jy1 < (unsigned)PR) &&                       \
                    ((unsigned)jx0 < (unsigned)PC) &&                       \
                    ((unsigned)jx1 < (unsigned)PC);                         \
        C.inp = __all(inp_);                                                \
        C.p00 = jy0 * PC + jx0; C.p01 = jy0 * PC + jx1;                     \
        C.p10 = jy1 * PC + jx0; C.p11 = jy1 * PC + jx1;                     \
        C.g00 = (y0c * WW + x0c) * 32 + (hi << 2);                          \
        C.g01 = (y0c * WW + x1c) * 32 + (hi << 2);                          \
        C.g10 = (y1c * WW + x0c) * 32 + (hi << 2);                          \
        C.g11 = (y1c * WW + x1c) * 32 + (hi << 2);                          \
    }

#define LDC(C, S, R00, R01, R10, R11) {                                     \
        if (C.inp) {                                                        \
            R00 = *(const u32x4*)&patch[PADDR(C.p00, 2 * (S) + hi)];        \
            R01 = *(const u32x4*)&patch[PADDR(C.p01, 2 * (S) + hi)];        \
            R10 = *(const u32x4*)&patch[PADDR(C.p10, 2 * (S) + hi)];        \
            R11 = *(const u32x4*)&patch[PADDR(C.p11, 2 * (S) + hi)];        \
        } else {                                                            \
            R00 = *(const u32x4*)(xb + C.g00 + (S) * 8);                    \
            R01 = *(const u32x4*)(xb + C.g01 + (S) * 8);                    \
            R10 = *(const u32x4*)(xb + C.g10 + (S) * 8);                    \
            R11 = *(const u32x4*)(xb + C.g11 + (S) * 8);                    \
        }                                                                   \
    }

#define DO_STEP(KK, S, C, R00, R01, R10, R11) {                             \
        f16x8 A0 = wAv[((KK) * 4 + (S)) * 64 + lane];                       \
        f16x8 A1 = wAv[(36 + (KK) * 4 + (S)) * 64 + lane];                  \
        f16x8 bf = bilerp_frag(R00, R01, R10, R11, C.W0, C.W1, C.W2, C.W3); \
        acc[0] = __builtin_amdgcn_mfma_f32_32x32x16_f16(A0, bf, acc[0], 0, 0, 0); \
        acc[1] = __builtin_amdgcn_mfma_f32_32x32x16_f16(A1, bf, acc[1], 0, 0, 0); \
    }

    {
        Ctx cc;
        MKCTX(0, 0, 0, cc);
        u32x4 r00, r01, r10, r11, n00, n01, n10, n11;
        LDC(cc, 0, r00, r01, r10, r11);

        int ky = 0, kx = 0;
        for (int kk = 0; kk < 9; ++kk) {
            // s=0: prefetch s=1, compute s=0
            LDC(cc, 1, n00, n01, n10, n11);
            DO_STEP(kk, 0, cc, r00, r01, r10, r11);
            r00 = n00; r01 = n01; r10 = n10; r11 = n11;
            // s=1: prefetch s=2
            LDC(cc, 2, n00, n01, n10, n11);
            DO_STEP(kk, 1, cc, r00, r01, r10, r11);
            r00 = n00; r01 = n01; r10 = n10; r11 = n11;
            // s=2: prefetch s=3
            LDC(cc, 3, n00, n01, n10, n11);
            DO_STEP(kk, 2, cc, r00, r01, r10, r11);
            r00 = n00; r01 = n01; r10 = n10; r11 = n11;
            // s=3: compute, then set up next kk
            DO_STEP(kk, 3, cc, r00, r01, r10, r11);
            if (kk < 8) {
                kx++; if (kx == 3) { kx = 0; ky++; }
                MKCTX(kk + 1, ky, kx, cc);
                LDC(cc, 0, r00, r01, r10, r11);
            }
        }
    }
#undef MKCTX
#undef LDC
#undef DO_STEP

    // D: row(cout) = m*32 + (r&3)+8*(r>>2)+4*hi, col(pixel) = q
#pragma unroll
    for (int m = 0; m < 2; ++m) {
#pragma unroll
        for (int r = 0; r < 16; ++r) {
            int cout = m * 32 + (r & 3) + 8 * (r >> 2) + 4 * hi;
            out[((size_t)b * 64 + cout) * HW + p] = acc[m][r];
        }
    }
}

// ---------------------------------------------------------------------------
extern "C" void kernel_launch(void* const* d_in, const int* in_sizes, int n_in,
                              void* d_out, int out_size, void* d_ws, size_t ws_size,
                              hipStream_t stream) {
    const float* x        = (const float*)d_in[0];
    const float* weight   = (const float*)d_in[1];
    const float* bias     = (const float*)d_in[2];
    const float* offset_w = (const float*)d_in[3];
    const float* offset_b = (const float*)d_in[4];
    float* out = (float*)d_out;

    unsigned int* xT = (unsigned int*)d_ws;                                // B*HW*32 u32 = 16MB
    unsigned short* wA  = (unsigned short*)(xT + (size_t)BATCH * HW * 32); // 4608*8
    unsigned short* owA = wA + 4608 * 8;                                   // 2304*8

    int n_tp = BATCH * HW / 64 + 27; // 2048 transform blocks + 27 prep blocks
    transform_prep_kernel<<<n_tp, 256, 0, stream>>>(x, xT, weight, offset_w, wA, owA);

    int n_blocks = BATCH * HW / 128; // 1024 blocks = 8 images x 128 tiles (8x16 px)
    fused_kernel<<<n_blocks, 256, 0, stream>>>(xT, wA, owA, bias, offset_b, out);
}

// Round 18
// 48.573 us; speedup vs baseline: 1.6576x; 1.6576x over previous
//
#include <hip/hip_runtime.h>
#include <hip/hip_bf16.h>
#include <math.h>

#define HH 128
#define WW 128
#define HW 16384
#define BATCH 8

// 2D tile geometry (fused kernel)
#define TR 8            // tile rows per block
#define TC 16           // tile cols per block
#define HALO 2
#define PR 12           // TR + 2*HALO
#define PC 20           // TC + 2*HALO
#define NPX (PR * PC)   // 240 patch pixels
#define PST 34          // dwords/px: 2 mod 32 -> 2-way banks on b128 (free)

typedef __attribute__((ext_vector_type(8))) _Float16 f16x8;
typedef __attribute__((ext_vector_type(2))) _Float16 f16x2;
typedef __attribute__((ext_vector_type(16))) float f32x16;
typedef __attribute__((ext_vector_type(4))) unsigned int u32x4;

union FragU { f16x8 v; unsigned int u[4]; u32x4 q; f16x2 h[4]; };

static __device__ __forceinline__ unsigned short f2h(float f) {
    _Float16 h = (_Float16)f;
    return *(unsigned short*)&h;
}
static __device__ __forceinline__ float h2f(unsigned short u) {
    _Float16 h = *(_Float16*)&u;
    return (float)h;
}

// f16 packed bilerp: 4 v_pk_fma_f16 per channel-pair; output IS the B-frag.
static __device__ __forceinline__ f16x8 bilerp_frag(
    u32x4 r00, u32x4 r01, u32x4 r10, u32x4 r11,
    f16x2 W0, f16x2 W1, f16x2 W2, f16x2 W3)
{
    FragU a, b, c, d, bf;
    a.q = r00; b.q = r01; c.q = r10; d.q = r11;
#pragma unroll
    for (int i = 0; i < 4; ++i) {
        f16x2 s = a.h[i] * W0;
        s = __builtin_elementwise_fma(b.h[i], W1, s);
        s = __builtin_elementwise_fma(c.h[i], W2, s);
        s = __builtin_elementwise_fma(d.h[i], W3, s);
        bf.h[i] = s;
    }
    return bf.v;
}

// plain stride-34 patch addressing
#define PADDR(PX, C) ((PX) * PST + ((C) << 2))

// ---------------------------------------------------------------------------
// Merged transform+prep kernel (r17; not implicated in the regression).
//   blocks [0,2048): x NCHW fp32 -> xT NHWC f16 (u32 pairs), LDS-tiled.
//   blocks [2048,2075): pack weights into 32x32x16 MFMA A-fragments (f16).
//     A lane l: row = l&31, k-elems j=0..7 -> channel c = s*16+8*(l>>5)+j
// ---------------------------------------------------------------------------
__global__ __launch_bounds__(256) void transform_prep_kernel(
    const float* __restrict__ x,
    unsigned int* __restrict__ xT,
    const float* __restrict__ weight,
    const float* __restrict__ offset_w,
    unsigned short* __restrict__ wA,
    unsigned short* __restrict__ owA)
{
    __shared__ unsigned int lds[64][33];
    int bid = blockIdx.x;
    int t = threadIdx.x;

    if (bid < 2048) {
        int b = bid & 7;                    // image -> XCD
        int pix0 = (bid >> 3) << 6;
        int px = t & 63;
        int cp0 = (t >> 6) * 8;

        const float* xb = x + (size_t)b * 64 * HW + pix0 + px;
#pragma unroll
        for (int it = 0; it < 8; ++it) {
            int cpair = cp0 + it;
            float lo = xb[(size_t)(2 * cpair) * HW];
            float hi = xb[(size_t)(2 * cpair + 1) * HW];
            lds[px][cpair] = ((unsigned int)f2h(hi) << 16) | f2h(lo);
        }
        __syncthreads();

        int wpx = t >> 2, qq = t & 3;
        unsigned int* dst = xT + ((size_t)b * HW + pix0 + wpx) * 32 + qq * 8;
        u32x4 a, c;
#pragma unroll
        for (int j = 0; j < 4; ++j) a[j] = lds[wpx][qq * 8 + j];
#pragma unroll
        for (int j = 0; j < 4; ++j) c[j] = lds[wpx][qq * 8 + 4 + j];
        *(u32x4*)dst = a;
        *(u32x4*)(dst + 4) = c;
        return;
    }

    // ---- prep branch ----
    int id = (bid - 2048) * 256 + t;
    if (id < 4608) {                        // 2*9*4*64
        int m = id / 2304;
        int rem = id % 2304;
        int kk = rem >> 8;
        int s = (rem >> 6) & 3;
        int l = id & 63;
        int cout = m * 32 + (l & 31);
        int cbase = s * 16 + 8 * (l >> 5);
#pragma unroll
        for (int j = 0; j < 8; ++j) {
            wA[id * 8 + j] = f2h(weight[(cout * 64 + cbase + j) * 9 + kk]);
        }
        return;
    }
    int id2 = id - 4608;
    if (id2 < 2304) {                       // 9*4*64
        int kk = id2 >> 8;
        int s = (id2 >> 6) & 3;
        int l = id2 & 63;
        int cout = l & 31;
        int cbase = s * 16 + 8 * (l >> 5);
#pragma unroll
        for (int j = 0; j < 8; ++j) {
            float v = (cout < 27) ? offset_w[(cout * 64 + cbase + j) * 9 + kk] : 0.0f;
            owA[id2 * 8 + j] = f2h(v);
        }
    }
}

// ---------------------------------------------------------------------------
// Fused kernel = r16 structure EXACTLY (39.3us proven), + #pragma unroll on
// the phase-2 kk loop. r17's lesson: the straight-line 4-step block behind
// ONE wave-uniform branch is already the pipelined form -- the compiler
// hoists all 16 ds_reads and uses counted lgkmcnt. Manual per-step prefetch
// with branches between prefetch and use forced lgkmcnt(0) drains at every
// control-flow join (fused 39->72us). Do not re-introduce.
// ---------------------------------------------------------------------------
__global__ __launch_bounds__(256, 4) void fused_kernel(
    const unsigned int* __restrict__ xT,    // NHWC f16
    const unsigned short* __restrict__ wA,  // (2,9,4,64,8) f16
    const unsigned short* __restrict__ owA, // (9,4,64,8) f16
    const float* __restrict__ bias,         // (64,)
    const float* __restrict__ offset_b,     // (27,)
    float* __restrict__ out)                // (B,64,HW) f32
{
    __shared__ unsigned int patch[NPX * PST];       // 32.64 KB
    __shared__ unsigned short red[4][27][32];       // 6.91 KB per-wave off/mask

    int t = threadIdx.x;
    int lane = t & 63;
    int wid = t >> 6;
    int bid = blockIdx.x;
    int b = bid & 7;                        // image -> XCD
    int tile = bid >> 3;                    // 0..127
    int ho0 = (tile >> 3) * TR;
    int wo0 = (tile & 7) * TC;
    int py0 = ho0 - HALO;
    int px0 = wo0 - HALO;

    int q = lane & 31;                      // pixel within wave
    int hi = lane >> 5;                     // channel-half
    int ho = ho0 + 2 * wid + (q >> 4);
    int wo = wo0 + (q & 15);
    int p = ho * WW + wo;

    const unsigned int* xb = xT + (size_t)b * HW * 32;
    const f16x8* wAv = (const f16x8*)wA;
    const f16x8* owAv = (const f16x8*)owA;

    // ---------------- stage patch (coalesced; OOB pixels -> zero) ---------
#pragma unroll
    for (int it = 0; it < 8; ++it) {
        int id = it * 256 + t;
        if (id < NPX * 8) {                 // 1920 16B-chunks
            int px = id >> 3;               // 8 lanes = 1 pixel
            int c = id & 7;
            int row = px / PC;
            int col = px - row * PC;
            int iy = py0 + row;
            int ix = px0 + col;
            bool okpx = ((unsigned)iy < 128u) && ((unsigned)ix < 128u);
            int yc = min(max(iy, 0), HH - 1);
            int xc = min(max(ix, 0), WW - 1);
            u32x4 v = *(const u32x4*)(xb + (size_t)(yc * WW + xc) * 32 + c * 4);
#pragma unroll
            for (int j = 0; j < 4; ++j) v[j] = okpx ? v[j] : 0u;
            *(u32x4*)&patch[PADDR(px, c)] = v;
        }
    }
    __syncthreads();                        // the ONLY barrier

    // ---------------- phase 1: offset conv (no boundary code) -------------
    {
        f32x16 acc1 = {};
#pragma unroll
        for (int kk = 0; kk < 9; ++kk) {
            int jy = ho + kk / 3 - 1 - py0;     // always within patch
            int jx = wo + kk % 3 - 1 - px0;
            int ptap = jy * PC + jx;
#pragma unroll
            for (int s = 0; s < 4; ++s) {
                FragU bf;
                bf.q = *(const u32x4*)&patch[PADDR(ptap, 2 * s + hi)];
                acc1 = __builtin_amdgcn_mfma_f32_32x32x16_f16(
                    owAv[(kk * 4 + s) * 64 + lane], bf.v, acc1, 0, 0, 0);
            }
        }
        // bias + sigmoid -> per-wave f16 LDS slice; acc1 dies here.
#pragma unroll
        for (int r = 0; r < 16; ++r) {
            int cout = (r & 3) + 8 * (r >> 2) + 4 * hi;
            if (cout < 27) {
                float a = acc1[r] + offset_b[cout];
                if (cout >= 18) a = 1.0f / (1.0f + __expf(-a));
                red[wid][cout][q] = f2h(a);
            }
        }
    }

    // ---------------- phase 2: deformable conv ----------------
    f32x16 acc[2];
#pragma unroll
    for (int m = 0; m < 2; ++m) {
#pragma unroll
        for (int r = 0; r < 16; ++r) {
            acc[m][r] = bias[m * 32 + (r & 3) + 8 * (r >> 2) + 4 * hi];
        }
    }

#pragma unroll
    for (int kk = 0; kk < 9; ++kk) {
        float dy = h2f(red[wid][2 * kk][q]);
        float dx = h2f(red[wid][2 * kk + 1][q]);
        float mm = h2f(red[wid][18 + kk][q]);

        float py = dy + (float)(kk / 3 + ho - 1);
        float px = dx + (float)(kk % 3 + wo - 1);
        float y0f = floorf(py), x0f = floorf(px);
        float wy = py - y0f, wx = px - x0f;
        int y0 = (int)y0f, x0 = (int)x0f;
        int y1 = y0 + 1, x1 = x0 + 1;
        bool y0ok = (unsigned)y0 < 128u, y1ok = (unsigned)y1 < 128u;
        bool x0ok = (unsigned)x0 < 128u, x1ok = (unsigned)x1 < 128u;
        float w0 = (y0ok && x0ok) ? (1.0f - wy) * (1.0f - wx) * mm : 0.0f;
        float w1 = (y0ok && x1ok) ? (1.0f - wy) * wx * mm : 0.0f;
        float w2 = (y1ok && x0ok) ? wy * (1.0f - wx) * mm : 0.0f;
        float w3 = (y1ok && x1ok) ? wy * wx * mm : 0.0f;
        int y0c = min(max(y0, 0), 127), y1c = min(max(y1, 0), 127);
        int x0c = min(max(x0, 0), 127), x1c = min(max(x1, 0), 127);

        f16x2 W0 = {(_Float16)w0, (_Float16)w0};
        f16x2 W1 = {(_Float16)w1, (_Float16)w1};
        f16x2 W2 = {(_Float16)w2, (_Float16)w2};
        f16x2 W3 = {(_Float16)w3, (_Float16)w3};

        int jy0 = y0c - py0, jy1 = y1c - py0;
        int jx0 = x0c - px0, jx1 = x1c - px0;
        bool inp = ((unsigned)jy0 < (unsigned)PR) && ((unsigned)jy1 < (unsigned)PR) &&
                   ((unsigned)jx0 < (unsigned)PC) && ((unsigned)jx1 < (unsigned)PC);

        // A-frags loaded just-in-time inside each step: only 2 live at once.
#define P2_STEP(S, R00, R01, R10, R11) {                                    \
            f16x8 A0 = wAv[(kk * 4 + (S)) * 64 + lane];                     \
            f16x8 A1 = wAv[(36 + kk * 4 + (S)) * 64 + lane];                \
            f16x8 bf = bilerp_frag(R00, R01, R10, R11, W0, W1, W2, W3);     \
            acc[0] = __builtin_amdgcn_mfma_f32_32x32x16_f16(A0, bf, acc[0], 0, 0, 0); \
            acc[1] = __builtin_amdgcn_mfma_f32_32x32x16_f16(A1, bf, acc[1], 0, 0, 0); \
        }

        if (__all(inp)) {
            int p00 = jy0 * PC + jx0;
            int p01 = jy0 * PC + jx1;
            int p10 = jy1 * PC + jx0;
            int p11 = jy1 * PC + jx1;
#define LRD(PX, S) (*(const u32x4*)&patch[PADDR(PX, 2 * (S) + hi)])
            P2_STEP(0, LRD(p00,0), LRD(p01,0), LRD(p10,0), LRD(p11,0));
            P2_STEP(1, LRD(p00,1), LRD(p01,1), LRD(p10,1), LRD(p11,1));
            P2_STEP(2, LRD(p00,2), LRD(p01,2), LRD(p10,2), LRD(p11,2));
            P2_STEP(3, LRD(p00,3), LRD(p01,3), LRD(p10,3), LRD(p11,3));
#undef LRD
        } else {
            int o00 = (y0c * WW + x0c) * 32 + (hi << 2);
            int o01 = (y0c * WW + x1c) * 32 + (hi << 2);
            int o10 = (y1c * WW + x0c) * 32 + (hi << 2);
            int o11 = (y1c * WW + x1c) * 32 + (hi << 2);
#define GRD(O, S) (*(const u32x4*)(xb + (O) + (S) * 8))
            P2_STEP(0, GRD(o00,0), GRD(o01,0), GRD(o10,0), GRD(o11,0));
            P2_STEP(1, GRD(o00,1), GRD(o01,1), GRD(o10,1), GRD(o11,1));
            P2_STEP(2, GRD(o00,2), GRD(o01,2), GRD(o10,2), GRD(o11,2));
            P2_STEP(3, GRD(o00,3), GRD(o01,3), GRD(o10,3), GRD(o11,3));
#undef GRD
        }
#undef P2_STEP
    }

    // D: row(cout) = m*32 + (r&3)+8*(r>>2)+4*hi, col(pixel) = q
#pragma unroll
    for (int m = 0; m < 2; ++m) {
#pragma unroll
        for (int r = 0; r < 16; ++r) {
            int cout = m * 32 + (r & 3) + 8 * (r >> 2) + 4 * hi;
            out[((size_t)b * 64 + cout) * HW + p] = acc[m][r];
        }
    }
}

// ---------------------------------------------------------------------------
extern "C" void kernel_launch(void* const* d_in, const int* in_sizes, int n_in,
                              void* d_out, int out_size, void* d_ws, size_t ws_size,
                              hipStream_t stream) {
    const float* x        = (const float*)d_in[0];
    const float* weight   = (const float*)d_in[1];
    const float* bias     = (const float*)d_in[2];
    const float* offset_w = (const float*)d_in[3];
    const float* offset_b = (const float*)d_in[4];
    float* out = (float*)d_out;

    unsigned int* xT = (unsigned int*)d_ws;                                // B*HW*32 u32 = 16MB
    unsigned short* wA  = (unsigned short*)(xT + (size_t)BATCH * HW * 32); // 4608*8
    unsigned short* owA = wA + 4608 * 8;                                   // 2304*8

    int n_tp = BATCH * HW / 64 + 27; // 2048 transform blocks + 27 prep blocks
    transform_prep_kernel<<<n_tp, 256, 0, stream>>>(x, xT, weight, offset_w, wA, owA);

    int n_blocks = BATCH * HW / 128; // 1024 blocks = 8 images x 128 tiles (8x16 px)
    fused_kernel<<<n_blocks, 256, 0, stream>>>(xT, wA, owA, bias, offset_b, out);
}